// Round 3
// baseline (2324.470 us; speedup 1.0000x reference)
//
#include <hip/hip_runtime.h>

#define NV   100000
#define NE   50000
#define NNZ  3200000
#define KIN  256
#define KOUT 64

#define NBE  782     // ceil(NE/64) edge buckets
#define NBV  1563    // ceil(NV/64) vertex buckets

// ---------------------------------------------------------------------------
// Kernel 1: Xp[r][o] = sum_k X[r][k] * W[o][k]
// ---------------------------------------------------------------------------
__global__ __launch_bounds__(256) void k_project(const float* __restrict__ X,
                                                 const float* __restrict__ W,
                                                 float* __restrict__ Xp) {
    __shared__ float Wt[KIN][KOUT];   // 64 KB
    const int tid = threadIdx.x;
    for (int i = tid; i < KIN * KOUT; i += 256) {
        int o = i & 63;
        int k = i >> 6;
        Wt[k][o] = W[o * KIN + k];
    }
    __syncthreads();

    const int g   = tid >> 4;
    const int t16 = tid & 15;
    const int ch0 = t16 << 2;
    const int rbase = blockIdx.x * 64 + g * 4;

    const float4* xp[4];
#pragma unroll
    for (int i = 0; i < 4; ++i) {
        int rr = rbase + i;
        if (rr > NV - 1) rr = NV - 1;
        xp[i] = (const float4*)(X + (size_t)rr * KIN);
    }

    float acc[4][4];
#pragma unroll
    for (int i = 0; i < 4; ++i)
#pragma unroll
        for (int c = 0; c < 4; ++c) acc[i][c] = 0.0f;

    for (int kk = 0; kk < KIN / 4; ++kk) {
        float4 w[4];
#pragma unroll
        for (int j = 0; j < 4; ++j)
            w[j] = *(const float4*)&Wt[4 * kk + j][ch0];
#pragma unroll
        for (int i = 0; i < 4; ++i) {
            float4 x = xp[i][kk];
            acc[i][0] = fmaf(x.x, w[0].x, acc[i][0]);
            acc[i][1] = fmaf(x.x, w[0].y, acc[i][1]);
            acc[i][2] = fmaf(x.x, w[0].z, acc[i][2]);
            acc[i][3] = fmaf(x.x, w[0].w, acc[i][3]);
            acc[i][0] = fmaf(x.y, w[1].x, acc[i][0]);
            acc[i][1] = fmaf(x.y, w[1].y, acc[i][1]);
            acc[i][2] = fmaf(x.y, w[1].z, acc[i][2]);
            acc[i][3] = fmaf(x.y, w[1].w, acc[i][3]);
            acc[i][0] = fmaf(x.z, w[2].x, acc[i][0]);
            acc[i][1] = fmaf(x.z, w[2].y, acc[i][1]);
            acc[i][2] = fmaf(x.z, w[2].z, acc[i][2]);
            acc[i][3] = fmaf(x.z, w[2].w, acc[i][3]);
            acc[i][0] = fmaf(x.w, w[3].x, acc[i][0]);
            acc[i][1] = fmaf(x.w, w[3].y, acc[i][1]);
            acc[i][2] = fmaf(x.w, w[3].z, acc[i][2]);
            acc[i][3] = fmaf(x.w, w[3].w, acc[i][3]);
        }
    }

#pragma unroll
    for (int i = 0; i < 4; ++i) {
        int r = rbase + i;
        if (r < NV) {
            float4 o = make_float4(acc[i][0], acc[i][1], acc[i][2], acc[i][3]);
            *(float4*)&Xp[(size_t)r * KOUT + ch0] = o;
        }
    }
}

// ---------------------------------------------------------------------------
// Bucket histogram for BOTH partitions (bucket = key >> 6)
// ---------------------------------------------------------------------------
__global__ __launch_bounds__(256) void k_bucket_hist(const int* __restrict__ v_idx,
                                                     const int* __restrict__ e_idx,
                                                     int* __restrict__ cntBE,
                                                     int* __restrict__ cntBV) {
    const int i = blockIdx.x * 256 + threadIdx.x;
    if (i < NNZ) {
        atomicAdd(&cntBE[e_idx[i] >> 6], 1);
        atomicAdd(&cntBV[v_idx[i] >> 6], 1);
    }
}

// Single-block exclusive scan (n <= a few thousand): off[0..n], cur copy.
__device__ void scan_one(const int* __restrict__ cnt, int* __restrict__ off,
                         int* __restrict__ cur, int n) {
    __shared__ int buf[1024];
    __shared__ int carry_s;
    const int tid = threadIdx.x;
    if (tid == 0) carry_s = 0;
    __syncthreads();
    for (int base = 0; base < n; base += 1024) {
        const int i = base + tid;
        const int v = (i < n) ? cnt[i] : 0;
        buf[tid] = v;
        __syncthreads();
        for (int d = 1; d < 1024; d <<= 1) {
            int t = (tid >= d) ? buf[tid - d] : 0;
            __syncthreads();
            buf[tid] += t;
            __syncthreads();
        }
        const int carry = carry_s;
        if (i < n) {
            const int excl = carry + buf[tid] - v;
            off[i] = excl;
            cur[i] = excl;
        }
        __syncthreads();
        if (tid == 1023) carry_s = carry + buf[1023];
        __syncthreads();
    }
    if (tid == 0) off[n] = carry_s;
    __syncthreads();
}

__global__ __launch_bounds__(1024) void k_bucket_scan(const int* cntBE, int* offBE, int* curBE,
                                                      const int* cntBV, int* offBV, int* curBV) {
    scan_one(cntBE, offBE, curBE, NBE);
    scan_one(cntBV, offBV, curBV, NBV);
}

// ---------------------------------------------------------------------------
// Partition: scatter packed (val | localKey<<17) into bucket-contiguous runs.
// val < 2^17 (v<100000, e<50000), localKey = key & 63.
// ---------------------------------------------------------------------------
__global__ __launch_bounds__(256) void k_partition(const int* __restrict__ key,
                                                   const int* __restrict__ val,
                                                   int* __restrict__ curB,
                                                   unsigned* __restrict__ part) {
    const int i = blockIdx.x * 256 + threadIdx.x;
    if (i < NNZ) {
        const int k = key[i];
        const int p = atomicAdd(&curB[k >> 6], 1);
        part[p] = (unsigned)val[i] | ((unsigned)(k & 63) << 17);
    }
}

// ---------------------------------------------------------------------------
// Per-bucket counting sort: one block per bucket (64 major keys).
// Emits offOut[] (global CSR offsets) and ordered adj[] values.
// ---------------------------------------------------------------------------
__global__ __launch_bounds__(256) void k_buildcsr(const unsigned* __restrict__ part,
                                                  const int* __restrict__ offB,
                                                  int* __restrict__ offOut,
                                                  int* __restrict__ adj,
                                                  int nMajor) {
    const int b = blockIdx.x;
    const int tid = threadIdx.x;
    const int base = offB[b];
    const int nb = offB[b + 1] - base;
    const int k0 = b << 6;

    __shared__ int hist[64], cur[64];
    if (tid < 64) hist[tid] = 0;
    __syncthreads();

    for (int i = tid; i < nb; i += 256)
        atomicAdd(&hist[(part[base + i] >> 17) & 63], 1);
    __syncthreads();

    if (tid == 0) {
        int s = 0;
        for (int k = 0; k < 64; ++k) {
            int h = hist[k];
            hist[k] = s;      // becomes exclusive prefix
            cur[k] = s;
            s += h;
        }
    }
    __syncthreads();

    const int lim = min(64, nMajor - k0);
    if (tid < lim) offOut[k0 + tid] = base + hist[tid];
    if (b == 0 && tid == 0) offOut[nMajor] = NNZ;

    for (int i = tid; i < nb; i += 256) {
        const unsigned u = part[base + i];
        const int lk = (u >> 17) & 63;
        adj[base + atomicAdd(&cur[lk], 1)] = (int)(u & 0x1FFFFu);
    }
}

// ---------------------------------------------------------------------------
// Stage 1 (pull): one wave per edge; lane = channel; 8x unrolled inner loop.
// ---------------------------------------------------------------------------
__global__ __launch_bounds__(256) void k_gatherE(const float* __restrict__ Xp,
                                                 const int* __restrict__ offE,
                                                 const int* __restrict__ adj,
                                                 const float* __restrict__ degE,
                                                 const float* __restrict__ Wdiag,
                                                 float* __restrict__ Xe) {
    const int wave = (blockIdx.x * 256 + threadIdx.x) >> 6;
    const int lane = threadIdx.x & 63;
    if (wave >= NE) return;
    const int b = offE[wave];
    const int e = offE[wave + 1];
    float acc = 0.0f;
    for (int base = b; base < e; base += 64) {
        const int m = min(64, e - base);
        const int vi = (base + lane < e) ? adj[base + lane] : 0;
        int t = 0;
        for (; t + 8 <= m; t += 8) {
            const int i0 = __shfl(vi, t + 0, 64);
            const int i1 = __shfl(vi, t + 1, 64);
            const int i2 = __shfl(vi, t + 2, 64);
            const int i3 = __shfl(vi, t + 3, 64);
            const int i4 = __shfl(vi, t + 4, 64);
            const int i5 = __shfl(vi, t + 5, 64);
            const int i6 = __shfl(vi, t + 6, 64);
            const int i7 = __shfl(vi, t + 7, 64);
            const float a0 = Xp[(size_t)i0 * KOUT + lane];
            const float a1 = Xp[(size_t)i1 * KOUT + lane];
            const float a2 = Xp[(size_t)i2 * KOUT + lane];
            const float a3 = Xp[(size_t)i3 * KOUT + lane];
            const float a4 = Xp[(size_t)i4 * KOUT + lane];
            const float a5 = Xp[(size_t)i5 * KOUT + lane];
            const float a6 = Xp[(size_t)i6 * KOUT + lane];
            const float a7 = Xp[(size_t)i7 * KOUT + lane];
            acc += ((a0 + a1) + (a2 + a3)) + ((a4 + a5) + (a6 + a7));
        }
        for (; t < m; ++t) {
            const int v = __shfl(vi, t, 64);
            acc += Xp[(size_t)v * KOUT + lane];
        }
    }
    Xe[(size_t)wave * KOUT + lane] = acc * (degE[wave] * Wdiag[wave]);
}

// ---------------------------------------------------------------------------
// Stage 2 (pull): one wave per vertex.
// ---------------------------------------------------------------------------
__global__ __launch_bounds__(256) void k_gatherV(const float* __restrict__ Xe,
                                                 const int* __restrict__ offV,
                                                 const int* __restrict__ adj,
                                                 const float* __restrict__ degV,
                                                 float* __restrict__ out) {
    const int wave = (blockIdx.x * 256 + threadIdx.x) >> 6;
    const int lane = threadIdx.x & 63;
    if (wave >= NV) return;
    const int b = offV[wave];
    const int e = offV[wave + 1];
    float acc = 0.0f;
    for (int base = b; base < e; base += 64) {
        const int m = min(64, e - base);
        const int ei = (base + lane < e) ? adj[base + lane] : 0;
        int t = 0;
        for (; t + 8 <= m; t += 8) {
            const int i0 = __shfl(ei, t + 0, 64);
            const int i1 = __shfl(ei, t + 1, 64);
            const int i2 = __shfl(ei, t + 2, 64);
            const int i3 = __shfl(ei, t + 3, 64);
            const int i4 = __shfl(ei, t + 4, 64);
            const int i5 = __shfl(ei, t + 5, 64);
            const int i6 = __shfl(ei, t + 6, 64);
            const int i7 = __shfl(ei, t + 7, 64);
            const float a0 = Xe[(size_t)i0 * KOUT + lane];
            const float a1 = Xe[(size_t)i1 * KOUT + lane];
            const float a2 = Xe[(size_t)i2 * KOUT + lane];
            const float a3 = Xe[(size_t)i3 * KOUT + lane];
            const float a4 = Xe[(size_t)i4 * KOUT + lane];
            const float a5 = Xe[(size_t)i5 * KOUT + lane];
            const float a6 = Xe[(size_t)i6 * KOUT + lane];
            const float a7 = Xe[(size_t)i7 * KOUT + lane];
            acc += ((a0 + a1) + (a2 + a3)) + ((a4 + a5) + (a6 + a7));
        }
        for (; t < m; ++t) {
            const int ee = __shfl(ei, t, 64);
            acc += Xe[(size_t)ee * KOUT + lane];
        }
    }
    out[(size_t)wave * KOUT + lane] = acc * degV[wave];
}

extern "C" void kernel_launch(void* const* d_in, const int* in_sizes, int n_in,
                              void* d_out, int out_size, void* d_ws, size_t ws_size,
                              hipStream_t stream) {
    const float* X     = (const float*)d_in[0];
    const float* W     = (const float*)d_in[1];
    const float* degE  = (const float*)d_in[2];
    const float* degV  = (const float*)d_in[3];
    const float* Wdiag = (const float*)d_in[4];
    const int*   v_idx = (const int*)d_in[5];
    const int*   e_idx = (const int*)d_in[6];
    float* out = (float*)d_out;

    // Workspace layout (~65 MB). adj and part are REUSED for E then V phases
    // (gatherE is ordered before buildcsr-V on the stream).
    float*    Xp   = (float*)d_ws;                       // 6.4M floats
    float*    Xe   = Xp + (size_t)NV * KOUT;             // 3.2M floats
    int*      adj  = (int*)(Xe + (size_t)NE * KOUT);     // 3.2M ints (E, then V)
    unsigned* part = (unsigned*)(adj + NNZ);             // 3.2M u32 (E, then V)
    int*      offE = (int*)(part + NNZ);                 // NE+1
    int*      offV = offE + (NE + 1);                    // NV+1
    int*      cntBE = offV + (NV + 1);                   // NBE
    int*      cntBV = cntBE + NBE;                       // NBV (contiguous w/ cntBE)
    int*      offBE = cntBV + NBV;                       // NBE+1
    int*      offBV = offBE + (NBE + 1);                 // NBV+1
    int*      curBE = offBV + (NBV + 1);                 // NBE
    int*      curBV = curBE + NBE;                       // NBV

    hipMemsetAsync(cntBE, 0, (size_t)(NBE + NBV) * sizeof(int), stream);

    k_project<<<(NV + 63) / 64, 256, 0, stream>>>(X, W, Xp);

    const int nblk_nnz = (NNZ + 255) / 256;   // 12500
    k_bucket_hist<<<nblk_nnz, 256, 0, stream>>>(v_idx, e_idx, cntBE, cntBV);
    k_bucket_scan<<<1, 1024, 0, stream>>>(cntBE, offBE, curBE, cntBV, offBV, curBV);

    // ---- Edge side: partition -> CSR -> gather
    k_partition<<<nblk_nnz, 256, 0, stream>>>(e_idx, v_idx, curBE, part);
    k_buildcsr<<<NBE, 256, 0, stream>>>(part, offBE, offE, adj, NE);
    k_gatherE<<<(NE * 64) / 256, 256, 0, stream>>>(Xp, offE, adj, degE, Wdiag, Xe);

    // ---- Vertex side: partition -> CSR -> gather (reuses part/adj)
    k_partition<<<nblk_nnz, 256, 0, stream>>>(v_idx, e_idx, curBV, part);
    k_buildcsr<<<NBV, 256, 0, stream>>>(part, offBV, offV, adj, NV);
    k_gatherV<<<(NV * 64) / 256, 256, 0, stream>>>(Xe, offV, adj, degV, out);
}

// Round 4
// 457.359 us; speedup vs baseline: 5.0824x; 5.0824x over previous
//
#include <hip/hip_runtime.h>

#define NV   100000
#define NE   50000
#define NNZ  3200000
#define KIN  256
#define KOUT 64

#define NB    320                  // partition blocks (NNZ % NB == 0)
#define CHUNK (NNZ / NB)           // 10000
#define NBE   782                  // ceil(NE/64) edge buckets
#define NBV   1563                 // ceil(NV/64) vertex buckets
#define NBINS (NBE + NBV)          // 2345
#define LSCAN (NBINS * NB)         // 750400
#define NBLK_SCAN ((LSCAN + 1023) / 1024)   // 733

// ---------------------------------------------------------------------------
// Kernel 1: Xp[r][o] = sum_k X[r][k] * W[o][k]
// ---------------------------------------------------------------------------
__global__ __launch_bounds__(256) void k_project(const float* __restrict__ X,
                                                 const float* __restrict__ W,
                                                 float* __restrict__ Xp) {
    __shared__ float Wt[KIN][KOUT];   // 64 KB
    const int tid = threadIdx.x;
    for (int i = tid; i < KIN * KOUT; i += 256) {
        int o = i & 63;
        int k = i >> 6;
        Wt[k][o] = W[o * KIN + k];
    }
    __syncthreads();

    const int g   = tid >> 4;
    const int t16 = tid & 15;
    const int ch0 = t16 << 2;
    const int rbase = blockIdx.x * 64 + g * 4;

    const float4* xp[4];
#pragma unroll
    for (int i = 0; i < 4; ++i) {
        int rr = rbase + i;
        if (rr > NV - 1) rr = NV - 1;
        xp[i] = (const float4*)(X + (size_t)rr * KIN);
    }

    float acc[4][4];
#pragma unroll
    for (int i = 0; i < 4; ++i)
#pragma unroll
        for (int c = 0; c < 4; ++c) acc[i][c] = 0.0f;

    for (int kk = 0; kk < KIN / 4; ++kk) {
        float4 w[4];
#pragma unroll
        for (int j = 0; j < 4; ++j)
            w[j] = *(const float4*)&Wt[4 * kk + j][ch0];
#pragma unroll
        for (int i = 0; i < 4; ++i) {
            float4 x = xp[i][kk];
            acc[i][0] = fmaf(x.x, w[0].x, acc[i][0]);
            acc[i][1] = fmaf(x.x, w[0].y, acc[i][1]);
            acc[i][2] = fmaf(x.x, w[0].z, acc[i][2]);
            acc[i][3] = fmaf(x.x, w[0].w, acc[i][3]);
            acc[i][0] = fmaf(x.y, w[1].x, acc[i][0]);
            acc[i][1] = fmaf(x.y, w[1].y, acc[i][1]);
            acc[i][2] = fmaf(x.y, w[1].z, acc[i][2]);
            acc[i][3] = fmaf(x.y, w[1].w, acc[i][3]);
            acc[i][0] = fmaf(x.z, w[2].x, acc[i][0]);
            acc[i][1] = fmaf(x.z, w[2].y, acc[i][1]);
            acc[i][2] = fmaf(x.z, w[2].z, acc[i][2]);
            acc[i][3] = fmaf(x.z, w[2].w, acc[i][3]);
            acc[i][0] = fmaf(x.w, w[3].x, acc[i][0]);
            acc[i][1] = fmaf(x.w, w[3].y, acc[i][1]);
            acc[i][2] = fmaf(x.w, w[3].z, acc[i][2]);
            acc[i][3] = fmaf(x.w, w[3].w, acc[i][3]);
        }
    }

#pragma unroll
    for (int i = 0; i < 4; ++i) {
        int r = rbase + i;
        if (r < NV) {
            float4 o = make_float4(acc[i][0], acc[i][1], acc[i][2], acc[i][3]);
            *(float4*)&Xp[(size_t)r * KOUT + ch0] = o;
        }
    }
}

// ---------------------------------------------------------------------------
// Per-block LDS histogram of BOTH bucket keys -> count matrix
// mat[bucket * NB + block]; E buckets [0,NBE), V buckets [NBE, NBINS)
// ---------------------------------------------------------------------------
__global__ __launch_bounds__(256) void k_hist(const int* __restrict__ v_idx,
                                              const int* __restrict__ e_idx,
                                              int* __restrict__ mat) {
    __shared__ int h[NBINS];
    const int b = blockIdx.x, tid = threadIdx.x;
    for (int i = tid; i < NBINS; i += 256) h[i] = 0;
    __syncthreads();
    const int base = b * CHUNK;
    for (int i = tid; i < CHUNK; i += 256) {
        atomicAdd(&h[e_idx[base + i] >> 6], 1);
        atomicAdd(&h[NBE + (v_idx[base + i] >> 6)], 1);
    }
    __syncthreads();
    for (int j = tid; j < NBINS; j += 256) mat[j * NB + b] = h[j];
}

// ---------------------------------------------------------------------------
// 3-kernel exclusive scan of mat[LSCAN]
// ---------------------------------------------------------------------------
__global__ __launch_bounds__(1024) void k_scan1(int* __restrict__ mat,
                                                int* __restrict__ bsum) {
    __shared__ int buf[1024];
    const int tid = threadIdx.x;
    const int i = blockIdx.x * 1024 + tid;
    const int v = (i < LSCAN) ? mat[i] : 0;
    buf[tid] = v;
    __syncthreads();
    for (int d = 1; d < 1024; d <<= 1) {
        int t = (tid >= d) ? buf[tid - d] : 0;
        __syncthreads();
        buf[tid] += t;
        __syncthreads();
    }
    if (i < LSCAN) mat[i] = buf[tid] - v;          // local exclusive
    if (tid == 1023) bsum[blockIdx.x] = buf[1023]; // block total
}

__global__ __launch_bounds__(1024) void k_scan2(int* __restrict__ bsum) {
    __shared__ int buf[1024];
    const int tid = threadIdx.x;
    const int v = (tid < NBLK_SCAN) ? bsum[tid] : 0;
    buf[tid] = v;
    __syncthreads();
    for (int d = 1; d < 1024; d <<= 1) {
        int t = (tid >= d) ? buf[tid - d] : 0;
        __syncthreads();
        buf[tid] += t;
        __syncthreads();
    }
    if (tid < NBLK_SCAN) bsum[tid] = buf[tid] - v; // exclusive block offsets
}

__global__ __launch_bounds__(1024) void k_scan3(int* __restrict__ mat,
                                                const int* __restrict__ bsum) {
    const int i = blockIdx.x * 1024 + threadIdx.x;
    if (i < LSCAN) mat[i] += bsum[blockIdx.x];
}

// ---------------------------------------------------------------------------
// Partition: cursors come from scanned matrix (LDS copies), no global atomics.
// part[p] = val | (localKey << 17)   (val < 2^17, localKey = key & 63)
// ---------------------------------------------------------------------------
__global__ __launch_bounds__(256) void k_partition(const int* __restrict__ key,
                                                   const int* __restrict__ val,
                                                   const int* __restrict__ mat,
                                                   int matOff, int sub, int nbkt,
                                                   unsigned* __restrict__ part) {
    extern __shared__ int cur[];   // nbkt ints
    const int b = blockIdx.x, tid = threadIdx.x;
    for (int j = tid; j < nbkt; j += 256)
        cur[j] = mat[matOff + j * NB + b] - sub;
    __syncthreads();
    const int base = b * CHUNK;
    for (int i = tid; i < CHUNK; i += 256) {
        const int k = key[base + i];
        const int p = atomicAdd(&cur[k >> 6], 1);
        part[p] = (unsigned)val[base + i] | ((unsigned)(k & 63) << 17);
    }
}

// ---------------------------------------------------------------------------
// Per-bucket counting sort -> CSR offsets + ordered adj
// ---------------------------------------------------------------------------
__global__ __launch_bounds__(256) void k_buildcsr(const unsigned* __restrict__ part,
                                                  const int* __restrict__ mat,
                                                  int matOff, int sub,
                                                  int* __restrict__ offOut,
                                                  int* __restrict__ adj,
                                                  int nMajor) {
    const int b = blockIdx.x;
    const int tid = threadIdx.x;
    const int base = mat[matOff + b * NB] - sub;
    const int end  = (b == (int)gridDim.x - 1) ? NNZ : (mat[matOff + (b + 1) * NB] - sub);
    const int nb = end - base;
    const int k0 = b << 6;

    __shared__ int hist[64], cur[64];
    if (tid < 64) hist[tid] = 0;
    __syncthreads();

    for (int i = tid; i < nb; i += 256)
        atomicAdd(&hist[(part[base + i] >> 17) & 63], 1);
    __syncthreads();

    if (tid == 0) {
        int s = 0;
        for (int k = 0; k < 64; ++k) {
            int h = hist[k];
            hist[k] = s;
            cur[k] = s;
            s += h;
        }
    }
    __syncthreads();

    const int lim = min(64, nMajor - k0);
    if (tid < lim) offOut[k0 + tid] = base + hist[tid];
    if (b == 0 && tid == 0) offOut[nMajor] = NNZ;

    for (int i = tid; i < nb; i += 256) {
        const unsigned u = part[base + i];
        const int lk = (u >> 17) & 63;
        adj[base + atomicAdd(&cur[lk], 1)] = (int)(u & 0x1FFFFu);
    }
}

// ---------------------------------------------------------------------------
// Stage 1 (pull): one wave per edge; lane = channel; 8x unrolled.
// ---------------------------------------------------------------------------
__global__ __launch_bounds__(256) void k_gatherE(const float* __restrict__ Xp,
                                                 const int* __restrict__ offE,
                                                 const int* __restrict__ adj,
                                                 const float* __restrict__ degE,
                                                 const float* __restrict__ Wdiag,
                                                 float* __restrict__ Xe) {
    const int wave = (blockIdx.x * 256 + threadIdx.x) >> 6;
    const int lane = threadIdx.x & 63;
    if (wave >= NE) return;
    const int b = offE[wave];
    const int e = offE[wave + 1];
    float acc = 0.0f;
    for (int base = b; base < e; base += 64) {
        const int m = min(64, e - base);
        const int vi = (base + lane < e) ? adj[base + lane] : 0;
        int t = 0;
        for (; t + 8 <= m; t += 8) {
            const int i0 = __shfl(vi, t + 0, 64);
            const int i1 = __shfl(vi, t + 1, 64);
            const int i2 = __shfl(vi, t + 2, 64);
            const int i3 = __shfl(vi, t + 3, 64);
            const int i4 = __shfl(vi, t + 4, 64);
            const int i5 = __shfl(vi, t + 5, 64);
            const int i6 = __shfl(vi, t + 6, 64);
            const int i7 = __shfl(vi, t + 7, 64);
            const float a0 = Xp[(size_t)i0 * KOUT + lane];
            const float a1 = Xp[(size_t)i1 * KOUT + lane];
            const float a2 = Xp[(size_t)i2 * KOUT + lane];
            const float a3 = Xp[(size_t)i3 * KOUT + lane];
            const float a4 = Xp[(size_t)i4 * KOUT + lane];
            const float a5 = Xp[(size_t)i5 * KOUT + lane];
            const float a6 = Xp[(size_t)i6 * KOUT + lane];
            const float a7 = Xp[(size_t)i7 * KOUT + lane];
            acc += ((a0 + a1) + (a2 + a3)) + ((a4 + a5) + (a6 + a7));
        }
        for (; t < m; ++t) {
            const int v = __shfl(vi, t, 64);
            acc += Xp[(size_t)v * KOUT + lane];
        }
    }
    Xe[(size_t)wave * KOUT + lane] = acc * (degE[wave] * Wdiag[wave]);
}

// ---------------------------------------------------------------------------
// Stage 2 (pull): one wave per vertex.
// ---------------------------------------------------------------------------
__global__ __launch_bounds__(256) void k_gatherV(const float* __restrict__ Xe,
                                                 const int* __restrict__ offV,
                                                 const int* __restrict__ adj,
                                                 const float* __restrict__ degV,
                                                 float* __restrict__ out) {
    const int wave = (blockIdx.x * 256 + threadIdx.x) >> 6;
    const int lane = threadIdx.x & 63;
    if (wave >= NV) return;
    const int b = offV[wave];
    const int e = offV[wave + 1];
    float acc = 0.0f;
    for (int base = b; base < e; base += 64) {
        const int m = min(64, e - base);
        const int ei = (base + lane < e) ? adj[base + lane] : 0;
        int t = 0;
        for (; t + 8 <= m; t += 8) {
            const int i0 = __shfl(ei, t + 0, 64);
            const int i1 = __shfl(ei, t + 1, 64);
            const int i2 = __shfl(ei, t + 2, 64);
            const int i3 = __shfl(ei, t + 3, 64);
            const int i4 = __shfl(ei, t + 4, 64);
            const int i5 = __shfl(ei, t + 5, 64);
            const int i6 = __shfl(ei, t + 6, 64);
            const int i7 = __shfl(ei, t + 7, 64);
            const float a0 = Xe[(size_t)i0 * KOUT + lane];
            const float a1 = Xe[(size_t)i1 * KOUT + lane];
            const float a2 = Xe[(size_t)i2 * KOUT + lane];
            const float a3 = Xe[(size_t)i3 * KOUT + lane];
            const float a4 = Xe[(size_t)i4 * KOUT + lane];
            const float a5 = Xe[(size_t)i5 * KOUT + lane];
            const float a6 = Xe[(size_t)i6 * KOUT + lane];
            const float a7 = Xe[(size_t)i7 * KOUT + lane];
            acc += ((a0 + a1) + (a2 + a3)) + ((a4 + a5) + (a6 + a7));
        }
        for (; t < m; ++t) {
            const int ee = __shfl(ei, t, 64);
            acc += Xe[(size_t)ee * KOUT + lane];
        }
    }
    out[(size_t)wave * KOUT + lane] = acc * degV[wave];
}

extern "C" void kernel_launch(void* const* d_in, const int* in_sizes, int n_in,
                              void* d_out, int out_size, void* d_ws, size_t ws_size,
                              hipStream_t stream) {
    const float* X     = (const float*)d_in[0];
    const float* W     = (const float*)d_in[1];
    const float* degE  = (const float*)d_in[2];
    const float* degV  = (const float*)d_in[3];
    const float* Wdiag = (const float*)d_in[4];
    const int*   v_idx = (const int*)d_in[5];
    const int*   e_idx = (const int*)d_in[6];
    float* out = (float*)d_out;

    // Workspace (~68 MB). part/adj reused for E then V phases (stream-ordered).
    float*    Xp   = (float*)d_ws;                       // NV*KOUT floats
    float*    Xe   = Xp + (size_t)NV * KOUT;             // NE*KOUT floats
    int*      adj  = (int*)(Xe + (size_t)NE * KOUT);     // NNZ
    unsigned* part = (unsigned*)(adj + NNZ);             // NNZ
    int*      offE = (int*)(part + NNZ);                 // NE+1
    int*      offV = offE + (NE + 1);                    // NV+1
    int*      mat  = offV + (NV + 1);                    // LSCAN
    int*      bsum = mat + LSCAN;                        // NBLK_SCAN

    k_project<<<(NV + 63) / 64, 256, 0, stream>>>(X, W, Xp);

    // Contention-free bucket counts + parallel exclusive scan
    k_hist<<<NB, 256, 0, stream>>>(v_idx, e_idx, mat);
    k_scan1<<<NBLK_SCAN, 1024, 0, stream>>>(mat, bsum);
    k_scan2<<<1, 1024, 0, stream>>>(bsum);
    k_scan3<<<NBLK_SCAN, 1024, 0, stream>>>(mat, bsum);

    // ---- Edge side: partition -> CSR -> gather
    k_partition<<<NB, 256, NBE * sizeof(int), stream>>>(e_idx, v_idx, mat, 0, 0, NBE, part);
    k_buildcsr<<<NBE, 256, 0, stream>>>(part, mat, 0, 0, offE, adj, NE);
    k_gatherE<<<(NE * 64) / 256, 256, 0, stream>>>(Xp, offE, adj, degE, Wdiag, Xe);

    // ---- Vertex side: partition -> CSR -> gather (reuses part/adj)
    k_partition<<<NB, 256, NBV * sizeof(int), stream>>>(v_idx, e_idx, mat, NBE * NB, NNZ, NBV, part);
    k_buildcsr<<<NBV, 256, 0, stream>>>(part, mat, NBE * NB, NNZ, offV, adj, NV);
    k_gatherV<<<(NV * 64) / 256, 256, 0, stream>>>(Xe, offV, adj, degV, out);
}

// Round 5
// 452.455 us; speedup vs baseline: 5.1375x; 1.0108x over previous
//
#include <hip/hip_runtime.h>

#define NV   100000
#define NE   50000
#define NNZ  3200000
#define KIN  256
#define KOUT 64

#define NB    400                  // partition/hist blocks (NNZ = 400*8000 exactly)
#define CHUNK (NNZ / NB)           // 8000
#define NBE   782                  // ceil(NE/64) edge buckets
#define NBV   1563                 // ceil(NV/64) vertex buckets
#define NBINS (NBE + NBV)          // 2345
#define LSCAN (NBINS * NB)         // 938000
#define NBLK_SCAN ((LSCAN + 1023) / 1024)   // 917 (must stay <= 1024 for k_scan2)

#define PKC   128                  // k_project K-chunk (Wt tile = 32 KB)

// ---------------------------------------------------------------------------
// Kernel 1: Xp[r][o] = sum_k X[r][k] * W[o][k]
// K-chunked W tile: 32 KB LDS -> 5 blocks/CU (was 64 KB -> 2 blocks/CU).
// Inner pattern identical to round 4 (measured SQ_LDS_BANK_CONFLICT = 0).
// ---------------------------------------------------------------------------
__global__ __launch_bounds__(256) void k_project(const float* __restrict__ X,
                                                 const float* __restrict__ W,
                                                 float* __restrict__ Xp) {
    __shared__ float Wt[PKC][KOUT];   // 32 KB
    const int tid = threadIdx.x;
    const int g   = tid >> 4;
    const int t16 = tid & 15;
    const int ch0 = t16 << 2;
    const int rbase = blockIdx.x * 64 + g * 4;

    const float4* xp[4];
#pragma unroll
    for (int i = 0; i < 4; ++i) {
        int rr = rbase + i;
        if (rr > NV - 1) rr = NV - 1;   // clamp reads; stores guarded below
        xp[i] = (const float4*)(X + (size_t)rr * KIN);
    }

    float acc[4][4];
#pragma unroll
    for (int i = 0; i < 4; ++i)
#pragma unroll
        for (int c = 0; c < 4; ++c) acc[i][c] = 0.0f;

    for (int k0 = 0; k0 < KIN; k0 += PKC) {
        __syncthreads();   // protect Wt against reuse from previous chunk
        for (int i = tid; i < PKC * KOUT; i += 256) {
            int o = i & 63;
            int k = i >> 6;
            Wt[k][o] = W[o * KIN + k0 + k];
        }
        __syncthreads();

        const int kq0 = k0 >> 2;
        for (int kk = 0; kk < PKC / 4; ++kk) {
            float4 w[4];
#pragma unroll
            for (int j = 0; j < 4; ++j)
                w[j] = *(const float4*)&Wt[4 * kk + j][ch0];
#pragma unroll
            for (int i = 0; i < 4; ++i) {
                float4 x = xp[i][kq0 + kk];
                acc[i][0] = fmaf(x.x, w[0].x, acc[i][0]);
                acc[i][1] = fmaf(x.x, w[0].y, acc[i][1]);
                acc[i][2] = fmaf(x.x, w[0].z, acc[i][2]);
                acc[i][3] = fmaf(x.x, w[0].w, acc[i][3]);
                acc[i][0] = fmaf(x.y, w[1].x, acc[i][0]);
                acc[i][1] = fmaf(x.y, w[1].y, acc[i][1]);
                acc[i][2] = fmaf(x.y, w[1].z, acc[i][2]);
                acc[i][3] = fmaf(x.y, w[1].w, acc[i][3]);
                acc[i][0] = fmaf(x.z, w[2].x, acc[i][0]);
                acc[i][1] = fmaf(x.z, w[2].y, acc[i][1]);
                acc[i][2] = fmaf(x.z, w[2].z, acc[i][2]);
                acc[i][3] = fmaf(x.z, w[2].w, acc[i][3]);
                acc[i][0] = fmaf(x.w, w[3].x, acc[i][0]);
                acc[i][1] = fmaf(x.w, w[3].y, acc[i][1]);
                acc[i][2] = fmaf(x.w, w[3].z, acc[i][2]);
                acc[i][3] = fmaf(x.w, w[3].w, acc[i][3]);
            }
        }
    }

#pragma unroll
    for (int i = 0; i < 4; ++i) {
        int r = rbase + i;
        if (r < NV) {
            float4 o = make_float4(acc[i][0], acc[i][1], acc[i][2], acc[i][3]);
            *(float4*)&Xp[(size_t)r * KOUT + ch0] = o;
        }
    }
}

// ---------------------------------------------------------------------------
// Per-block LDS histogram of BOTH bucket keys -> count matrix
// mat[bucket * NB + block]; E buckets [0,NBE), V buckets [NBE, NBINS)
// ---------------------------------------------------------------------------
__global__ __launch_bounds__(256) void k_hist(const int* __restrict__ v_idx,
                                              const int* __restrict__ e_idx,
                                              int* __restrict__ mat) {
    __shared__ int h[NBINS];
    const int b = blockIdx.x, tid = threadIdx.x;
    for (int i = tid; i < NBINS; i += 256) h[i] = 0;
    __syncthreads();
    const int base = b * CHUNK;
    for (int i = tid; i < CHUNK; i += 256) {
        atomicAdd(&h[e_idx[base + i] >> 6], 1);
        atomicAdd(&h[NBE + (v_idx[base + i] >> 6)], 1);
    }
    __syncthreads();
    for (int j = tid; j < NBINS; j += 256) mat[j * NB + b] = h[j];
}

// ---------------------------------------------------------------------------
// 3-kernel exclusive scan of mat[LSCAN]
// ---------------------------------------------------------------------------
__global__ __launch_bounds__(1024) void k_scan1(int* __restrict__ mat,
                                                int* __restrict__ bsum) {
    __shared__ int buf[1024];
    const int tid = threadIdx.x;
    const int i = blockIdx.x * 1024 + tid;
    const int v = (i < LSCAN) ? mat[i] : 0;
    buf[tid] = v;
    __syncthreads();
    for (int d = 1; d < 1024; d <<= 1) {
        int t = (tid >= d) ? buf[tid - d] : 0;
        __syncthreads();
        buf[tid] += t;
        __syncthreads();
    }
    if (i < LSCAN) mat[i] = buf[tid] - v;          // local exclusive
    if (tid == 1023) bsum[blockIdx.x] = buf[1023]; // block total
}

__global__ __launch_bounds__(1024) void k_scan2(int* __restrict__ bsum) {
    __shared__ int buf[1024];
    const int tid = threadIdx.x;
    const int v = (tid < NBLK_SCAN) ? bsum[tid] : 0;
    buf[tid] = v;
    __syncthreads();
    for (int d = 1; d < 1024; d <<= 1) {
        int t = (tid >= d) ? buf[tid - d] : 0;
        __syncthreads();
        buf[tid] += t;
        __syncthreads();
    }
    if (tid < NBLK_SCAN) bsum[tid] = buf[tid] - v; // exclusive block offsets
}

__global__ __launch_bounds__(1024) void k_scan3(int* __restrict__ mat,
                                                const int* __restrict__ bsum) {
    const int i = blockIdx.x * 1024 + threadIdx.x;
    if (i < LSCAN) mat[i] += bsum[blockIdx.x];
}

// ---------------------------------------------------------------------------
// Partition: cursors come from scanned matrix (LDS copies), no global atomics.
// part[p] = val | (localKey << 17)   (val < 2^17, localKey = key & 63)
// ---------------------------------------------------------------------------
__global__ __launch_bounds__(256) void k_partition(const int* __restrict__ key,
                                                   const int* __restrict__ val,
                                                   const int* __restrict__ mat,
                                                   int matOff, int sub, int nbkt,
                                                   unsigned* __restrict__ part) {
    extern __shared__ int cur[];   // nbkt ints
    const int b = blockIdx.x, tid = threadIdx.x;
    for (int j = tid; j < nbkt; j += 256)
        cur[j] = mat[matOff + j * NB + b] - sub;
    __syncthreads();
    const int base = b * CHUNK;
    for (int i = tid; i < CHUNK; i += 256) {
        const int k = key[base + i];
        const int p = atomicAdd(&cur[k >> 6], 1);
        part[p] = (unsigned)val[base + i] | ((unsigned)(k & 63) << 17);
    }
}

// ---------------------------------------------------------------------------
// Per-bucket counting sort -> CSR offsets + ordered adj
// ---------------------------------------------------------------------------
__global__ __launch_bounds__(256) void k_buildcsr(const unsigned* __restrict__ part,
                                                  const int* __restrict__ mat,
                                                  int matOff, int sub,
                                                  int* __restrict__ offOut,
                                                  int* __restrict__ adj,
                                                  int nMajor) {
    const int b = blockIdx.x;
    const int tid = threadIdx.x;
    const int base = mat[matOff + b * NB] - sub;
    const int end  = (b == (int)gridDim.x - 1) ? NNZ : (mat[matOff + (b + 1) * NB] - sub);
    const int nb = end - base;
    const int k0 = b << 6;

    __shared__ int hist[64], cur[64];
    if (tid < 64) hist[tid] = 0;
    __syncthreads();

    for (int i = tid; i < nb; i += 256)
        atomicAdd(&hist[(part[base + i] >> 17) & 63], 1);
    __syncthreads();

    if (tid == 0) {
        int s = 0;
        for (int k = 0; k < 64; ++k) {
            int h = hist[k];
            hist[k] = s;
            cur[k] = s;
            s += h;
        }
    }
    __syncthreads();

    const int lim = min(64, nMajor - k0);
    if (tid < lim) offOut[k0 + tid] = base + hist[tid];
    if (b == 0 && tid == 0) offOut[nMajor] = NNZ;

    for (int i = tid; i < nb; i += 256) {
        const unsigned u = part[base + i];
        const int lk = (u >> 17) & 63;
        adj[base + atomicAdd(&cur[lk], 1)] = (int)(u & 0x1FFFFu);
    }
}

// ---------------------------------------------------------------------------
// Stage 1 (pull): one wave per edge; lane = channel; 8x unrolled.
// ---------------------------------------------------------------------------
__global__ __launch_bounds__(256) void k_gatherE(const float* __restrict__ Xp,
                                                 const int* __restrict__ offE,
                                                 const int* __restrict__ adj,
                                                 const float* __restrict__ degE,
                                                 const float* __restrict__ Wdiag,
                                                 float* __restrict__ Xe) {
    const int wave = (blockIdx.x * 256 + threadIdx.x) >> 6;
    const int lane = threadIdx.x & 63;
    if (wave >= NE) return;
    const int b = offE[wave];
    const int e = offE[wave + 1];
    float acc = 0.0f;
    for (int base = b; base < e; base += 64) {
        const int m = min(64, e - base);
        const int vi = (base + lane < e) ? adj[base + lane] : 0;
        int t = 0;
        for (; t + 8 <= m; t += 8) {
            const int i0 = __shfl(vi, t + 0, 64);
            const int i1 = __shfl(vi, t + 1, 64);
            const int i2 = __shfl(vi, t + 2, 64);
            const int i3 = __shfl(vi, t + 3, 64);
            const int i4 = __shfl(vi, t + 4, 64);
            const int i5 = __shfl(vi, t + 5, 64);
            const int i6 = __shfl(vi, t + 6, 64);
            const int i7 = __shfl(vi, t + 7, 64);
            const float a0 = Xp[(size_t)i0 * KOUT + lane];
            const float a1 = Xp[(size_t)i1 * KOUT + lane];
            const float a2 = Xp[(size_t)i2 * KOUT + lane];
            const float a3 = Xp[(size_t)i3 * KOUT + lane];
            const float a4 = Xp[(size_t)i4 * KOUT + lane];
            const float a5 = Xp[(size_t)i5 * KOUT + lane];
            const float a6 = Xp[(size_t)i6 * KOUT + lane];
            const float a7 = Xp[(size_t)i7 * KOUT + lane];
            acc += ((a0 + a1) + (a2 + a3)) + ((a4 + a5) + (a6 + a7));
        }
        for (; t < m; ++t) {
            const int v = __shfl(vi, t, 64);
            acc += Xp[(size_t)v * KOUT + lane];
        }
    }
    Xe[(size_t)wave * KOUT + lane] = acc * (degE[wave] * Wdiag[wave]);
}

// ---------------------------------------------------------------------------
// Stage 2 (pull): one wave per vertex.
// ---------------------------------------------------------------------------
__global__ __launch_bounds__(256) void k_gatherV(const float* __restrict__ Xe,
                                                 const int* __restrict__ offV,
                                                 const int* __restrict__ adj,
                                                 const float* __restrict__ degV,
                                                 float* __restrict__ out) {
    const int wave = (blockIdx.x * 256 + threadIdx.x) >> 6;
    const int lane = threadIdx.x & 63;
    if (wave >= NV) return;
    const int b = offV[wave];
    const int e = offV[wave + 1];
    float acc = 0.0f;
    for (int base = b; base < e; base += 64) {
        const int m = min(64, e - base);
        const int ei = (base + lane < e) ? adj[base + lane] : 0;
        int t = 0;
        for (; t + 8 <= m; t += 8) {
            const int i0 = __shfl(ei, t + 0, 64);
            const int i1 = __shfl(ei, t + 1, 64);
            const int i2 = __shfl(ei, t + 2, 64);
            const int i3 = __shfl(ei, t + 3, 64);
            const int i4 = __shfl(ei, t + 4, 64);
            const int i5 = __shfl(ei, t + 5, 64);
            const int i6 = __shfl(ei, t + 6, 64);
            const int i7 = __shfl(ei, t + 7, 64);
            const float a0 = Xe[(size_t)i0 * KOUT + lane];
            const float a1 = Xe[(size_t)i1 * KOUT + lane];
            const float a2 = Xe[(size_t)i2 * KOUT + lane];
            const float a3 = Xe[(size_t)i3 * KOUT + lane];
            const float a4 = Xe[(size_t)i4 * KOUT + lane];
            const float a5 = Xe[(size_t)i5 * KOUT + lane];
            const float a6 = Xe[(size_t)i6 * KOUT + lane];
            const float a7 = Xe[(size_t)i7 * KOUT + lane];
            acc += ((a0 + a1) + (a2 + a3)) + ((a4 + a5) + (a6 + a7));
        }
        for (; t < m; ++t) {
            const int ee = __shfl(ei, t, 64);
            acc += Xe[(size_t)ee * KOUT + lane];
        }
    }
    out[(size_t)wave * KOUT + lane] = acc * degV[wave];
}

extern "C" void kernel_launch(void* const* d_in, const int* in_sizes, int n_in,
                              void* d_out, int out_size, void* d_ws, size_t ws_size,
                              hipStream_t stream) {
    const float* X     = (const float*)d_in[0];
    const float* W     = (const float*)d_in[1];
    const float* degE  = (const float*)d_in[2];
    const float* degV  = (const float*)d_in[3];
    const float* Wdiag = (const float*)d_in[4];
    const int*   v_idx = (const int*)d_in[5];
    const int*   e_idx = (const int*)d_in[6];
    float* out = (float*)d_out;

    // Workspace (~68 MB). part/adj reused for E then V phases (stream-ordered).
    float*    Xp   = (float*)d_ws;                       // NV*KOUT floats
    float*    Xe   = Xp + (size_t)NV * KOUT;             // NE*KOUT floats
    int*      adj  = (int*)(Xe + (size_t)NE * KOUT);     // NNZ
    unsigned* part = (unsigned*)(adj + NNZ);             // NNZ
    int*      offE = (int*)(part + NNZ);                 // NE+1
    int*      offV = offE + (NE + 1);                    // NV+1
    int*      mat  = offV + (NV + 1);                    // LSCAN
    int*      bsum = mat + LSCAN;                        // NBLK_SCAN

    k_project<<<(NV + 63) / 64, 256, 0, stream>>>(X, W, Xp);

    // Contention-free bucket counts + parallel exclusive scan
    k_hist<<<NB, 256, 0, stream>>>(v_idx, e_idx, mat);
    k_scan1<<<NBLK_SCAN, 1024, 0, stream>>>(mat, bsum);
    k_scan2<<<1, 1024, 0, stream>>>(bsum);
    k_scan3<<<NBLK_SCAN, 1024, 0, stream>>>(mat, bsum);

    // ---- Edge side: partition -> CSR -> gather
    k_partition<<<NB, 256, NBE * sizeof(int), stream>>>(e_idx, v_idx, mat, 0, 0, NBE, part);
    k_buildcsr<<<NBE, 256, 0, stream>>>(part, mat, 0, 0, offE, adj, NE);
    k_gatherE<<<(NE * 64) / 256, 256, 0, stream>>>(Xp, offE, adj, degE, Wdiag, Xe);

    // ---- Vertex side: partition -> CSR -> gather (reuses part/adj)
    k_partition<<<NB, 256, NBV * sizeof(int), stream>>>(v_idx, e_idx, mat, NBE * NB, NNZ, NBV, part);
    k_buildcsr<<<NBV, 256, 0, stream>>>(part, mat, NBE * NB, NNZ, offV, adj, NV);
    k_gatherV<<<(NV * 64) / 256, 256, 0, stream>>>(Xe, offV, adj, degV, out);
}

// Round 6
// 446.100 us; speedup vs baseline: 5.2107x; 1.0142x over previous
//
#include <hip/hip_runtime.h>

#define NV   100000
#define NE   50000
#define NNZ  3200000
#define KIN  256
#define KOUT 64

#define NB    400                  // partition/hist blocks (NNZ = 400*8000 exactly)
#define CHUNK (NNZ / NB)           // 8000
#define NBE   782                  // ceil(NE/64) edge buckets
#define NBV   1563                 // ceil(NV/64) vertex buckets
#define NBINS (NBE + NBV)          // 2345
#define LSCAN (NBINS * NB)         // 938000
#define NBLK_SCAN ((LSCAN + 1023) / 1024)   // 917 (must stay <= 1024 for k_scan2)

#define PROWS 128                  // k_project tile rows
#define PKC   64                   // k_project K-chunk
#define XS_LD 68                   // Xs padded stride (floats): 16B-aligned, conflict-free reads

// ---------------------------------------------------------------------------
// Tiny one-off: Wt[k][o] = W[o][k]  (64 KB, makes all GEMM staging coalesced)
// ---------------------------------------------------------------------------
__global__ __launch_bounds__(256) void k_wt(const float* __restrict__ W,
                                            float* __restrict__ Wt) {
    const int o = blockIdx.x;          // 0..63
    const int k = threadIdx.x;         // 0..255
    Wt[k * KOUT + o] = W[o * KIN + k];
}

// ---------------------------------------------------------------------------
// Kernel 1: Xp[r][o] = sum_k X[r][k] * W[o][k]
// LDS-staged X tile + reg-double-buffered staging (loads for chunk c+1 issue
// before compute of chunk c). Thread = 4 rows (stride 32) x 8 ch.
// ---------------------------------------------------------------------------
__global__ __launch_bounds__(256) void k_project(const float* __restrict__ X,
                                                 const float* __restrict__ Wt,
                                                 float* __restrict__ Xp) {
    __shared__ float Xs[PROWS * XS_LD];   // 34.8 KB
    __shared__ float Ws[PKC * KOUT];      // 16 KB   (k-major: Ws[k][o])

    const int tid = threadIdx.x;
    const int rbase = blockIdx.x * PROWS;
    const int rg = tid >> 3;              // 0..31 -> rows rg, rg+32, rg+64, rg+96
    const int c8 = (tid & 7) * 8;         // 8 channels per thread

    float4 xr[8], wr[4];

    // prologue: stage chunk 0 into regs (coalesced float4 loads)
#pragma unroll
    for (int j = 0; j < 8; ++j) {
        const int idx = tid + 256 * j;            // 0..2047
        const int row = idx >> 4, kq = idx & 15;  // 128 rows x 16 float4
        const int r = min(rbase + row, NV - 1);
        xr[j] = *(const float4*)&X[(size_t)r * KIN + kq * 4];
    }
#pragma unroll
    for (int j = 0; j < 4; ++j) {
        const int idx = tid + 256 * j;            // 0..1023
        const int k = idx >> 4, oq = idx & 15;    // 64 k x 16 float4
        wr[j] = *(const float4*)&Wt[(size_t)k * KOUT + oq * 4];
    }

    float acc[4][8];
#pragma unroll
    for (int i = 0; i < 4; ++i)
#pragma unroll
        for (int c = 0; c < 8; ++c) acc[i][c] = 0.0f;

    for (int ch = 0; ch < KIN / PKC; ++ch) {
        __syncthreads();   // all waves done reading LDS from previous chunk
#pragma unroll
        for (int j = 0; j < 8; ++j) {
            const int idx = tid + 256 * j;
            const int row = idx >> 4, kq = idx & 15;
            *(float4*)&Xs[row * XS_LD + kq * 4] = xr[j];
        }
#pragma unroll
        for (int j = 0; j < 4; ++j) {
            const int idx = tid + 256 * j;
            const int k = idx >> 4, oq = idx & 15;
            *(float4*)&Ws[k * KOUT + oq * 4] = wr[j];
        }
        __syncthreads();

        if (ch < KIN / PKC - 1) {
            const int kc = (ch + 1) * PKC;
#pragma unroll
            for (int j = 0; j < 8; ++j) {
                const int idx = tid + 256 * j;
                const int row = idx >> 4, kq = idx & 15;
                const int r = min(rbase + row, NV - 1);
                xr[j] = *(const float4*)&X[(size_t)r * KIN + kc + kq * 4];
            }
#pragma unroll
            for (int j = 0; j < 4; ++j) {
                const int idx = tid + 256 * j;
                const int k = idx >> 4, oq = idx & 15;
                wr[j] = *(const float4*)&Wt[(size_t)(kc + k) * KOUT + oq * 4];
            }
        }

        // compute chunk: 16 k-quads, 12 ds_read_b128 -> 128 FMA each
        for (int kk = 0; kk < PKC / 4; ++kk) {
            float4 xv[4], wva[4], wvb[4];
#pragma unroll
            for (int i = 0; i < 4; ++i)
                xv[i] = *(const float4*)&Xs[(rg + 32 * i) * XS_LD + kk * 4];
#pragma unroll
            for (int j = 0; j < 4; ++j) {
                wva[j] = *(const float4*)&Ws[(kk * 4 + j) * KOUT + c8];
                wvb[j] = *(const float4*)&Ws[(kk * 4 + j) * KOUT + c8 + 4];
            }
#pragma unroll
            for (int i = 0; i < 4; ++i) {
                const float x0 = xv[i].x, x1 = xv[i].y, x2 = xv[i].z, x3 = xv[i].w;
                acc[i][0] = fmaf(x0, wva[0].x, acc[i][0]);
                acc[i][1] = fmaf(x0, wva[0].y, acc[i][1]);
                acc[i][2] = fmaf(x0, wva[0].z, acc[i][2]);
                acc[i][3] = fmaf(x0, wva[0].w, acc[i][3]);
                acc[i][4] = fmaf(x0, wvb[0].x, acc[i][4]);
                acc[i][5] = fmaf(x0, wvb[0].y, acc[i][5]);
                acc[i][6] = fmaf(x0, wvb[0].z, acc[i][6]);
                acc[i][7] = fmaf(x0, wvb[0].w, acc[i][7]);
                acc[i][0] = fmaf(x1, wva[1].x, acc[i][0]);
                acc[i][1] = fmaf(x1, wva[1].y, acc[i][1]);
                acc[i][2] = fmaf(x1, wva[1].z, acc[i][2]);
                acc[i][3] = fmaf(x1, wva[1].w, acc[i][3]);
                acc[i][4] = fmaf(x1, wvb[1].x, acc[i][4]);
                acc[i][5] = fmaf(x1, wvb[1].y, acc[i][5]);
                acc[i][6] = fmaf(x1, wvb[1].z, acc[i][6]);
                acc[i][7] = fmaf(x1, wvb[1].w, acc[i][7]);
                acc[i][0] = fmaf(x2, wva[2].x, acc[i][0]);
                acc[i][1] = fmaf(x2, wva[2].y, acc[i][1]);
                acc[i][2] = fmaf(x2, wva[2].z, acc[i][2]);
                acc[i][3] = fmaf(x2, wva[2].w, acc[i][3]);
                acc[i][4] = fmaf(x2, wvb[2].x, acc[i][4]);
                acc[i][5] = fmaf(x2, wvb[2].y, acc[i][5]);
                acc[i][6] = fmaf(x2, wvb[2].z, acc[i][6]);
                acc[i][7] = fmaf(x2, wvb[2].w, acc[i][7]);
                acc[i][0] = fmaf(x3, wva[3].x, acc[i][0]);
                acc[i][1] = fmaf(x3, wva[3].y, acc[i][1]);
                acc[i][2] = fmaf(x3, wva[3].z, acc[i][2]);
                acc[i][3] = fmaf(x3, wva[3].w, acc[i][3]);
                acc[i][4] = fmaf(x3, wvb[3].x, acc[i][4]);
                acc[i][5] = fmaf(x3, wvb[3].y, acc[i][5]);
                acc[i][6] = fmaf(x3, wvb[3].z, acc[i][6]);
                acc[i][7] = fmaf(x3, wvb[3].w, acc[i][7]);
            }
        }
    }

#pragma unroll
    for (int i = 0; i < 4; ++i) {
        const int r = rbase + rg + 32 * i;
        if (r < NV) {
            *(float4*)&Xp[(size_t)r * KOUT + c8] =
                make_float4(acc[i][0], acc[i][1], acc[i][2], acc[i][3]);
            *(float4*)&Xp[(size_t)r * KOUT + c8 + 4] =
                make_float4(acc[i][4], acc[i][5], acc[i][6], acc[i][7]);
        }
    }
}

// ---------------------------------------------------------------------------
// Per-block LDS histogram of BOTH bucket keys -> count matrix
// mat[bucket * NB + block]; E buckets [0,NBE), V buckets [NBE, NBINS)
// ---------------------------------------------------------------------------
__global__ __launch_bounds__(256) void k_hist(const int* __restrict__ v_idx,
                                              const int* __restrict__ e_idx,
                                              int* __restrict__ mat) {
    __shared__ int h[NBINS];
    const int b = blockIdx.x, tid = threadIdx.x;
    for (int i = tid; i < NBINS; i += 256) h[i] = 0;
    __syncthreads();
    const int base = b * CHUNK;
    for (int i = tid; i < CHUNK; i += 256) {
        atomicAdd(&h[e_idx[base + i] >> 6], 1);
        atomicAdd(&h[NBE + (v_idx[base + i] >> 6)], 1);
    }
    __syncthreads();
    for (int j = tid; j < NBINS; j += 256) mat[j * NB + b] = h[j];
}

// ---------------------------------------------------------------------------
// 3-kernel exclusive scan of mat[LSCAN]
// ---------------------------------------------------------------------------
__global__ __launch_bounds__(1024) void k_scan1(int* __restrict__ mat,
                                                int* __restrict__ bsum) {
    __shared__ int buf[1024];
    const int tid = threadIdx.x;
    const int i = blockIdx.x * 1024 + tid;
    const int v = (i < LSCAN) ? mat[i] : 0;
    buf[tid] = v;
    __syncthreads();
    for (int d = 1; d < 1024; d <<= 1) {
        int t = (tid >= d) ? buf[tid - d] : 0;
        __syncthreads();
        buf[tid] += t;
        __syncthreads();
    }
    if (i < LSCAN) mat[i] = buf[tid] - v;          // local exclusive
    if (tid == 1023) bsum[blockIdx.x] = buf[1023]; // block total
}

__global__ __launch_bounds__(1024) void k_scan2(int* __restrict__ bsum) {
    __shared__ int buf[1024];
    const int tid = threadIdx.x;
    const int v = (tid < NBLK_SCAN) ? bsum[tid] : 0;
    buf[tid] = v;
    __syncthreads();
    for (int d = 1; d < 1024; d <<= 1) {
        int t = (tid >= d) ? buf[tid - d] : 0;
        __syncthreads();
        buf[tid] += t;
        __syncthreads();
    }
    if (tid < NBLK_SCAN) bsum[tid] = buf[tid] - v; // exclusive block offsets
}

__global__ __launch_bounds__(1024) void k_scan3(int* __restrict__ mat,
                                                const int* __restrict__ bsum) {
    const int i = blockIdx.x * 1024 + threadIdx.x;
    if (i < LSCAN) mat[i] += bsum[blockIdx.x];
}

// ---------------------------------------------------------------------------
// Partition: cursors come from scanned matrix (LDS copies), no global atomics.
// part[p] = val | (localKey << 17)   (val < 2^17, localKey = key & 63)
// ---------------------------------------------------------------------------
__global__ __launch_bounds__(256) void k_partition(const int* __restrict__ key,
                                                   const int* __restrict__ val,
                                                   const int* __restrict__ mat,
                                                   int matOff, int sub, int nbkt,
                                                   unsigned* __restrict__ part) {
    extern __shared__ int cur[];   // nbkt ints
    const int b = blockIdx.x, tid = threadIdx.x;
    for (int j = tid; j < nbkt; j += 256)
        cur[j] = mat[matOff + j * NB + b] - sub;
    __syncthreads();
    const int base = b * CHUNK;
    for (int i = tid; i < CHUNK; i += 256) {
        const int k = key[base + i];
        const int p = atomicAdd(&cur[k >> 6], 1);
        part[p] = (unsigned)val[base + i] | ((unsigned)(k & 63) << 17);
    }
}

// ---------------------------------------------------------------------------
// Per-bucket counting sort -> CSR offsets + ordered adj
// ---------------------------------------------------------------------------
__global__ __launch_bounds__(256) void k_buildcsr(const unsigned* __restrict__ part,
                                                  const int* __restrict__ mat,
                                                  int matOff, int sub,
                                                  int* __restrict__ offOut,
                                                  int* __restrict__ adj,
                                                  int nMajor) {
    const int b = blockIdx.x;
    const int tid = threadIdx.x;
    const int base = mat[matOff + b * NB] - sub;
    const int end  = (b == (int)gridDim.x - 1) ? NNZ : (mat[matOff + (b + 1) * NB] - sub);
    const int nb = end - base;
    const int k0 = b << 6;

    __shared__ int hist[64], cur[64];
    if (tid < 64) hist[tid] = 0;
    __syncthreads();

    for (int i = tid; i < nb; i += 256)
        atomicAdd(&hist[(part[base + i] >> 17) & 63], 1);
    __syncthreads();

    if (tid == 0) {
        int s = 0;
        for (int k = 0; k < 64; ++k) {
            int h = hist[k];
            hist[k] = s;
            cur[k] = s;
            s += h;
        }
    }
    __syncthreads();

    const int lim = min(64, nMajor - k0);
    if (tid < lim) offOut[k0 + tid] = base + hist[tid];
    if (b == 0 && tid == 0) offOut[nMajor] = NNZ;

    for (int i = tid; i < nb; i += 256) {
        const unsigned u = part[base + i];
        const int lk = (u >> 17) & 63;
        adj[base + atomicAdd(&cur[lk], 1)] = (int)(u & 0x1FFFFu);
    }
}

// ---------------------------------------------------------------------------
// Stage 1 (pull): one wave per edge; lane = channel; 8x unrolled.
// ---------------------------------------------------------------------------
__global__ __launch_bounds__(256) void k_gatherE(const float* __restrict__ Xp,
                                                 const int* __restrict__ offE,
                                                 const int* __restrict__ adj,
                                                 const float* __restrict__ degE,
                                                 const float* __restrict__ Wdiag,
                                                 float* __restrict__ Xe) {
    const int wave = (blockIdx.x * 256 + threadIdx.x) >> 6;
    const int lane = threadIdx.x & 63;
    if (wave >= NE) return;
    const int b = offE[wave];
    const int e = offE[wave + 1];
    float acc = 0.0f;
    for (int base = b; base < e; base += 64) {
        const int m = min(64, e - base);
        const int vi = (base + lane < e) ? adj[base + lane] : 0;
        int t = 0;
        for (; t + 8 <= m; t += 8) {
            const int i0 = __shfl(vi, t + 0, 64);
            const int i1 = __shfl(vi, t + 1, 64);
            const int i2 = __shfl(vi, t + 2, 64);
            const int i3 = __shfl(vi, t + 3, 64);
            const int i4 = __shfl(vi, t + 4, 64);
            const int i5 = __shfl(vi, t + 5, 64);
            const int i6 = __shfl(vi, t + 6, 64);
            const int i7 = __shfl(vi, t + 7, 64);
            const float a0 = Xp[(size_t)i0 * KOUT + lane];
            const float a1 = Xp[(size_t)i1 * KOUT + lane];
            const float a2 = Xp[(size_t)i2 * KOUT + lane];
            const float a3 = Xp[(size_t)i3 * KOUT + lane];
            const float a4 = Xp[(size_t)i4 * KOUT + lane];
            const float a5 = Xp[(size_t)i5 * KOUT + lane];
            const float a6 = Xp[(size_t)i6 * KOUT + lane];
            const float a7 = Xp[(size_t)i7 * KOUT + lane];
            acc += ((a0 + a1) + (a2 + a3)) + ((a4 + a5) + (a6 + a7));
        }
        for (; t < m; ++t) {
            const int v = __shfl(vi, t, 64);
            acc += Xp[(size_t)v * KOUT + lane];
        }
    }
    Xe[(size_t)wave * KOUT + lane] = acc * (degE[wave] * Wdiag[wave]);
}

// ---------------------------------------------------------------------------
// Stage 2 (pull): one wave per vertex.
// ---------------------------------------------------------------------------
__global__ __launch_bounds__(256) void k_gatherV(const float* __restrict__ Xe,
                                                 const int* __restrict__ offV,
                                                 const int* __restrict__ adj,
                                                 const float* __restrict__ degV,
                                                 float* __restrict__ out) {
    const int wave = (blockIdx.x * 256 + threadIdx.x) >> 6;
    const int lane = threadIdx.x & 63;
    if (wave >= NV) return;
    const int b = offV[wave];
    const int e = offV[wave + 1];
    float acc = 0.0f;
    for (int base = b; base < e; base += 64) {
        const int m = min(64, e - base);
        const int ei = (base + lane < e) ? adj[base + lane] : 0;
        int t = 0;
        for (; t + 8 <= m; t += 8) {
            const int i0 = __shfl(ei, t + 0, 64);
            const int i1 = __shfl(ei, t + 1, 64);
            const int i2 = __shfl(ei, t + 2, 64);
            const int i3 = __shfl(ei, t + 3, 64);
            const int i4 = __shfl(ei, t + 4, 64);
            const int i5 = __shfl(ei, t + 5, 64);
            const int i6 = __shfl(ei, t + 6, 64);
            const int i7 = __shfl(ei, t + 7, 64);
            const float a0 = Xe[(size_t)i0 * KOUT + lane];
            const float a1 = Xe[(size_t)i1 * KOUT + lane];
            const float a2 = Xe[(size_t)i2 * KOUT + lane];
            const float a3 = Xe[(size_t)i3 * KOUT + lane];
            const float a4 = Xe[(size_t)i4 * KOUT + lane];
            const float a5 = Xe[(size_t)i5 * KOUT + lane];
            const float a6 = Xe[(size_t)i6 * KOUT + lane];
            const float a7 = Xe[(size_t)i7 * KOUT + lane];
            acc += ((a0 + a1) + (a2 + a3)) + ((a4 + a5) + (a6 + a7));
        }
        for (; t < m; ++t) {
            const int ee = __shfl(ei, t, 64);
            acc += Xe[(size_t)ee * KOUT + lane];
        }
    }
    out[(size_t)wave * KOUT + lane] = acc * degV[wave];
}

extern "C" void kernel_launch(void* const* d_in, const int* in_sizes, int n_in,
                              void* d_out, int out_size, void* d_ws, size_t ws_size,
                              hipStream_t stream) {
    const float* X     = (const float*)d_in[0];
    const float* W     = (const float*)d_in[1];
    const float* degE  = (const float*)d_in[2];
    const float* degV  = (const float*)d_in[3];
    const float* Wdiag = (const float*)d_in[4];
    const int*   v_idx = (const int*)d_in[5];
    const int*   e_idx = (const int*)d_in[6];
    float* out = (float*)d_out;

    // Workspace (~68.5 MB). part/adj reused for E then V phases (stream-ordered).
    float*    Xp   = (float*)d_ws;                       // NV*KOUT floats
    float*    Xe   = Xp + (size_t)NV * KOUT;             // NE*KOUT floats
    int*      adj  = (int*)(Xe + (size_t)NE * KOUT);     // NNZ
    unsigned* part = (unsigned*)(adj + NNZ);             // NNZ
    int*      offE = (int*)(part + NNZ);                 // NE+1
    int*      offV = offE + (NE + 1);                    // NV+1
    int*      mat  = offV + (NV + 1);                    // LSCAN
    int*      bsum = mat + LSCAN;                        // NBLK_SCAN
    float*    Wt   = (float*)(bsum + NBLK_SCAN);         // KIN*KOUT (64 KB)

    k_wt<<<KOUT, KIN, 0, stream>>>(W, Wt);
    k_project<<<(NV + PROWS - 1) / PROWS, 256, 0, stream>>>(X, Wt, Xp);

    // Contention-free bucket counts + parallel exclusive scan
    k_hist<<<NB, 256, 0, stream>>>(v_idx, e_idx, mat);
    k_scan1<<<NBLK_SCAN, 1024, 0, stream>>>(mat, bsum);
    k_scan2<<<1, 1024, 0, stream>>>(bsum);
    k_scan3<<<NBLK_SCAN, 1024, 0, stream>>>(mat, bsum);

    // ---- Edge side: partition -> CSR -> gather
    k_partition<<<NB, 256, NBE * sizeof(int), stream>>>(e_idx, v_idx, mat, 0, 0, NBE, part);
    k_buildcsr<<<NBE, 256, 0, stream>>>(part, mat, 0, 0, offE, adj, NE);
    k_gatherE<<<(NE * 64) / 256, 256, 0, stream>>>(Xp, offE, adj, degE, Wdiag, Xe);

    // ---- Vertex side: partition -> CSR -> gather (reuses part/adj)
    k_partition<<<NB, 256, NBV * sizeof(int), stream>>>(v_idx, e_idx, mat, NBE * NB, NNZ, NBV, part);
    k_buildcsr<<<NBV, 256, 0, stream>>>(part, mat, NBE * NB, NNZ, offV, adj, NV);
    k_gatherV<<<(NV * 64) / 256, 256, 0, stream>>>(Xe, offV, adj, degV, out);
}